// Round 5
// baseline (171.037 us; speedup 1.0000x reference)
//
#include <hip/hip_runtime.h>
#include <hip/hip_fp16.h>

typedef _Float16 f16;
typedef _Float16 half8 __attribute__((ext_vector_type(8)));
typedef float f32x4 __attribute__((ext_vector_type(4)));

#define BATCH 8
#define NTOK 2048
#define FIN 256
#define FOUT 256
#define ALPHA 0.2f
#define WHS 2080   // WhT row stride (pad breaks 4KB power-of-2 stride)

// ---------------- K0: W[k][o] fp32 -> WT[o][k] fp16 ----------------
__global__ void k_wt(const float* __restrict__ W, f16* __restrict__ WT) {
    __shared__ float t[32][33];
    int o0 = blockIdx.x * 32, k0 = blockIdx.y * 32;
    int tx = threadIdx.x, ty = threadIdx.y;
    t[ty][tx] = W[(k0 + ty) * FOUT + o0 + tx];
    __syncthreads();
    WT[(o0 + ty) * FIN + (k0 + tx)] = (f16)t[tx][ty];
}

// ---------------- K pack: adj int32 -> bitmask ----------------
__global__ __launch_bounds__(256) void k_pack(const int* __restrict__ adj,
                                              unsigned long long* __restrict__ mask) {
    int lane = threadIdx.x & 63;
    size_t wv = (((size_t)blockIdx.x * 256 + threadIdx.x) >> 6);
    for (int it = 0; it < 8; it++) {
        size_t wave = wv + (size_t)it * 16384;
        const int* base = adj + wave * 256;
        unsigned long long m0 = __ballot(base[lane] > 0);
        unsigned long long m1 = __ballot(base[64 + lane] > 0);
        unsigned long long m2 = __ballot(base[128 + lane] > 0);
        unsigned long long m3 = __ballot(base[192 + lane] > 0);
        if (lane < 4) {
            unsigned long long v = lane == 0 ? m0 : lane == 1 ? m1 : lane == 2 ? m2 : m3;
            mask[wave * 4 + lane] = v;
        }
    }
}

// ---------------- K1: Wh = x @ W, store WhT[b][o][n] fp16 ----------------
__global__ __launch_bounds__(256) void k_gemm(const float* __restrict__ x,
                                              const f16* __restrict__ WT,
                                              f16* __restrict__ WhT) {
    __shared__ f16 Ah[64][72];
    __shared__ f16 Bt[256][72];
    int m0 = blockIdx.x * 64;
    int t = threadIdx.x;
    int lane = t & 63, w = t >> 6;
    f32x4 acc[4][4] = {};

    for (int k0 = 0; k0 < FIN; k0 += 64) {
        {
            int r = t >> 2, c = (t & 3) * 16;
            const float* src = x + (size_t)(m0 + r) * FIN + k0 + c;
            f16 tmp[16];
#pragma unroll
            for (int q = 0; q < 16; q++) tmp[q] = (f16)src[q];
            *(half8*)&Ah[r][c] = *(half8*)&tmp[0];
            *(half8*)&Ah[r][c + 8] = *(half8*)&tmp[8];
        }
        {
            const f16* src = WT + (size_t)t * FIN + k0;
#pragma unroll
            for (int q = 0; q < 8; q++)
                *(half8*)&Bt[t][q * 8] = *(const half8*)&src[q * 8];
        }
        __syncthreads();
#pragma unroll
        for (int kc = 0; kc < 2; kc++) {
            int krow = kc * 32 + ((lane >> 4) * 8);
            half8 af[4], bf[4];
#pragma unroll
            for (int fi = 0; fi < 4; fi++)
                af[fi] = *(half8*)&Ah[fi * 16 + (lane & 15)][krow];
#pragma unroll
            for (int fo = 0; fo < 4; fo++)
                bf[fo] = *(half8*)&Bt[w * 64 + fo * 16 + (lane & 15)][krow];
#pragma unroll
            for (int fi = 0; fi < 4; fi++)
#pragma unroll
                for (int fo = 0; fo < 4; fo++)
                    acc[fi][fo] = __builtin_amdgcn_mfma_f32_16x16x32_f16(
                        af[fi], bf[fo], acc[fi][fo], 0, 0, 0);
        }
        __syncthreads();
    }
    int b = m0 >> 11;
    int nbase = m0 & (NTOK - 1);
#pragma unroll
    for (int fi = 0; fi < 4; fi++)
#pragma unroll
        for (int fo = 0; fo < 4; fo++) {
            int o = w * 64 + fo * 16 + (lane & 15);
#pragma unroll
            for (int q = 0; q < 4; q++) {
                int n = nbase + fi * 16 + (lane >> 4) * 4 + q;
                WhT[((size_t)b * FOUT + o) * WHS + n] = (f16)acc[fi][fo][q];
            }
        }
}

// ---------------- K2: s1 = Wh@a1, s2 = Wh@a2 ----------------
__global__ __launch_bounds__(256) void k_s12(const f16* __restrict__ WhT,
                                             const float* __restrict__ a,
                                             float* __restrict__ s1,
                                             float* __restrict__ s2) {
    int b = blockIdx.y;
    int n = blockIdx.x * 256 + threadIdx.x;
    const f16* base = WhT + (size_t)b * FOUT * WHS + n;
    float a1 = 0.f, a2 = 0.f;
#pragma unroll 4
    for (int o = 0; o < FOUT; o++) {
        float wh = (float)base[(size_t)o * WHS];
        a1 += wh * a[o];
        a2 += wh * a[FOUT + o];
    }
    s1[b * NTOK + n] = a1;
    s2[b * NTOK + n] = a2;
}

// ---------------- K3: fused masked softmax + P@Wh + ELU ----------------
// 512 thr = 8 waves: rg=w&1 (32-row half of 64-row block), oh=(w>>1)&1 (128 o),
// kc=w>>2 (32-j half of each 64-j step; flash-combined at end).
// Per 64-j step: block reg-stages WhT slab (256 o x 64 j) into XOR-swizzled
// double-buffered LDS; one barrier/step; stage loads issued 1 step early.
__global__ __launch_bounds__(512, 2) void k_attn(const unsigned long long* __restrict__ mask,
                                                 const f16* __restrict__ WhT,
                                                 const float* __restrict__ s1g,
                                                 const float* __restrict__ s2g,
                                                 float* __restrict__ out) {
    __shared__ float s2_lds[NTOK];                    // 8 KB
    __shared__ __align__(16) f16 Bl[2][256][64];      // 64 KB, 16B-block XOR swizzle
    __shared__ float ml_lds[2][2][64];                // [kc][m|l][row]
    float (*accx)[132] = (float (*)[132])&Bl[0][0][0];  // combine staging (aliases Bl)

    int b = blockIdx.x & 7;                // batch -> XCD pinning
    int i0 = (blockIdx.x >> 3) * 64;
    int t = threadIdx.x;
    int lane = t & 63, w = t >> 6;
    int rg = w & 1, oh = (w >> 1) & 1, kc = w >> 2;
    int lr = lane & 15, lg = lane >> 4;

    // s2 -> LDS (512 thr x float4 == 2048)
    ((f32x4*)s2_lds)[t] = ((const f32x4*)(s2g + (size_t)b * NTOK))[t];

    // ---- staging setup: thread t stages row srow, 32-f16 half shalf ----
    int srow = t >> 1, shalf = t & 1;
    const f16* ssrc = WhT + ((size_t)(b * FOUT + srow)) * WHS + shalf * 32;
    f16* sdst0 = &Bl[0][0][0] + srow * 64;
    int sw[4];
#pragma unroll
    for (int i = 0; i < 4; i++) sw[i] = (((shalf * 4 + i) ^ (srow & 7)) * 8);

    int4 st[4];
#pragma unroll
    for (int i = 0; i < 4; i++) st[i] = *(const int4*)(ssrc + i * 8);      // jt=0
#pragma unroll
    for (int i = 0; i < 4; i++) *(int4*)(sdst0 + sw[i]) = st[i];           // -> buf0
#pragma unroll
    for (int i = 0; i < 4; i++) st[i] = *(const int4*)(ssrc + 64 + i * 8); // jt=1

    int row0 = i0 + rg * 32 + lr;
    float s1r0 = s1g[(size_t)b * NTOK + row0];
    float s1r1 = s1g[(size_t)b * NTOK + row0 + 16];
    const unsigned long long* mrow0 = mask + ((size_t)(b * NTOK + row0)) * 32;
    const unsigned long long* mrow1 = mrow0 + 16 * 32;
    unsigned long long mn0 = mrow0[0], mn1 = mrow1[0];

    float m0 = -3.0e38f, l0 = 0.f, m1 = -3.0e38f, l1 = 0.f;
    f32x4 acc0[8] = {}, acc1[8] = {};
    int msh = kc * 32 + lg * 8;
    int rsw = (((kc * 4 + lg) ^ (lr & 7)) * 8);   // swizzled j-offset for B reads

    __syncthreads();

    for (int jt = 0; jt < 32; jt++) {
        int buf = jt & 1;
        unsigned long long mk0 = mn0, mk1 = mn1;
        if (jt < 31) { mn0 = mrow0[jt + 1]; mn1 = mrow1[jt + 1]; }

        int jb = jt * 64 + msh;
        f32x4 sA = *(const f32x4*)&s2_lds[jb];
        f32x4 sB = *(const f32x4*)&s2_lds[jb + 4];
        float sv[8] = {sA[0], sA[1], sA[2], sA[3], sB[0], sB[1], sB[2], sB[3]};

        half8 ph0, ph1;
        float scl0, scl1;
        {   // fi = 0
            unsigned bits = (unsigned)(mk0 >> msh) & 0xffu;
            float e[8], lm = -3.0e38f;
#pragma unroll
            for (int q = 0; q < 8; q++) {
                float s = s1r0 + sv[q];
                float ev = fmaxf(s, ALPHA * s);
                e[q] = ev;
                if ((bits >> q) & 1) lm = fmaxf(lm, ev);
            }
            lm = fmaxf(lm, __shfl_xor(lm, 16));
            lm = fmaxf(lm, __shfl_xor(lm, 32));
            float mnew = fmaxf(m0, lm);
            scl0 = __expf(m0 - mnew);
            float ts = 0.f;
#pragma unroll
            for (int q = 0; q < 8; q++) {
                float p = ((bits >> q) & 1) ? __expf(e[q] - mnew) : 0.f;
                ts += p;
                ph0[q] = (f16)p;
            }
            ts += __shfl_xor(ts, 16);
            ts += __shfl_xor(ts, 32);
            l0 = l0 * scl0 + ts;
            m0 = mnew;
        }
        {   // fi = 1
            unsigned bits = (unsigned)(mk1 >> msh) & 0xffu;
            float e[8], lm = -3.0e38f;
#pragma unroll
            for (int q = 0; q < 8; q++) {
                float s = s1r1 + sv[q];
                float ev = fmaxf(s, ALPHA * s);
                e[q] = ev;
                if ((bits >> q) & 1) lm = fmaxf(lm, ev);
            }
            lm = fmaxf(lm, __shfl_xor(lm, 16));
            lm = fmaxf(lm, __shfl_xor(lm, 32));
            float mnew = fmaxf(m1, lm);
            scl1 = __expf(m1 - mnew);
            float ts = 0.f;
#pragma unroll
            for (int q = 0; q < 8; q++) {
                float p = ((bits >> q) & 1) ? __expf(e[q] - mnew) : 0.f;
                ts += p;
                ph1[q] = (f16)p;
            }
            ts += __shfl_xor(ts, 16);
            ts += __shfl_xor(ts, 32);
            l1 = l1 * scl1 + ts;
            m1 = mnew;
        }

        f32x4 r0, r1;
#pragma unroll
        for (int q = 0; q < 4; q++) {
            r0[q] = __shfl(scl0, lg * 4 + q);
            r1[q] = __shfl(scl1, lg * 4 + q);
        }
#pragma unroll
        for (int ot = 0; ot < 8; ot++) { acc0[ot] *= r0; acc1[ot] *= r1; }

        const f16* blds = &Bl[buf][0][0] + rsw + (oh * 128 + lr) * 64;
#pragma unroll
        for (int ot = 0; ot < 8; ot++) {
            half8 bfv = *(const half8*)(blds + ot * 16 * 64);
            acc0[ot] = __builtin_amdgcn_mfma_f32_16x16x32_f16(ph0, bfv, acc0[ot], 0, 0, 0);
            acc1[ot] = __builtin_amdgcn_mfma_f32_16x16x32_f16(ph1, bfv, acc1[ot], 0, 0, 0);
        }

        if (jt < 31) {
            f16* sdst = &Bl[buf ^ 1][0][0] + srow * 64;
#pragma unroll
            for (int i = 0; i < 4; i++) *(int4*)(sdst + sw[i]) = st[i];
            if (jt < 30) {
                const f16* nsrc = ssrc + (jt + 2) * 64;
#pragma unroll
                for (int i = 0; i < 4; i++) st[i] = *(const int4*)(nsrc + i * 8);
            }
        }
        __syncthreads();
    }

    if (oh == 0 && lane < 16) {
        ml_lds[kc][0][rg * 32 + lane] = m0;
        ml_lds[kc][1][rg * 32 + lane] = l0;
        ml_lds[kc][0][rg * 32 + 16 + lane] = m1;
        ml_lds[kc][1][rg * 32 + 16 + lane] = l1;
    }
    __syncthreads();

    // flash combine of the two kc streams; 2 rounds of 4 o-tiles
#pragma unroll
    for (int c = 0; c < 2; c++) {
        if (kc == 1) {
#pragma unroll
            for (int fi = 0; fi < 2; fi++)
#pragma unroll
                for (int q = 0; q < 4; q++) {
                    int rr = rg * 32 + fi * 16 + lg * 4 + q;
                    float ma = ml_lds[0][0][rr], mb = ml_lds[1][0][rr];
                    float f1 = __expf(mb - fmaxf(ma, mb));
#pragma unroll
                    for (int ol = 0; ol < 4; ol++) {
                        float v = (fi ? acc1[c * 4 + ol][q] : acc0[c * 4 + ol][q]) * f1;
                        accx[rr][oh * 64 + ol * 16 + lr] = v;
                    }
                }
        }
        __syncthreads();
        if (kc == 0) {
#pragma unroll
            for (int fi = 0; fi < 2; fi++)
#pragma unroll
                for (int q = 0; q < 4; q++) {
                    int rr = rg * 32 + fi * 16 + lg * 4 + q;
                    float ma = ml_lds[0][0][rr], mb = ml_lds[1][0][rr];
                    float mt = fmaxf(ma, mb);
                    float f0 = __expf(ma - mt), f1 = __expf(mb - mt);
                    float lt = ml_lds[0][1][rr] * f0 + ml_lds[1][1][rr] * f1;
                    float rl = 1.f / lt;
#pragma unroll
                    for (int ol = 0; ol < 4; ol++) {
                        int o = oh * 128 + (c * 4 + ol) * 16 + lr;
                        float v = ((fi ? acc1[c * 4 + ol][q] : acc0[c * 4 + ol][q]) * f0 +
                                   accx[rr][oh * 64 + ol * 16 + lr]) * rl;
                        v = v > 0.f ? v : __expf(v) - 1.f;
                        __builtin_nontemporal_store(
                            v, &out[((size_t)(b * NTOK + i0 + rr)) * FOUT + o]);
                    }
                }
        }
        __syncthreads();
    }
}

extern "C" void kernel_launch(void* const* d_in, const int* in_sizes, int n_in,
                              void* d_out, int out_size, void* d_ws, size_t ws_size,
                              hipStream_t stream) {
    const float* x = (const float*)d_in[0];
    const int* adj = (const int*)d_in[1];
    const float* W = (const float*)d_in[2];
    const float* a = (const float*)d_in[3];
    float* out = (float*)d_out;

    char* ws = (char*)d_ws;
    f16* WT = (f16*)ws;                                     // 128 KB
    f16* WhT = (f16*)(ws + 131072);                         // 8.13 MB
    float* s1 = (float*)(ws + 131072 + 8519680);            // 64 KB
    float* s2 = s1 + BATCH * NTOK;                          // 64 KB
    unsigned long long* mask64 =
        (unsigned long long*)(ws + 131072 + 8519680 + 131072);  // 4 MB

    k_wt<<<dim3(FOUT / 32, FIN / 32), dim3(32, 32), 0, stream>>>(W, WT);
    k_gemm<<<dim3(BATCH * NTOK / 64), 256, 0, stream>>>(x, WT, WhT);
    k_s12<<<dim3(NTOK / 256, BATCH), 256, 0, stream>>>(WhT, a, s1, s2);
    k_pack<<<dim3(4096), 256, 0, stream>>>(adj, mask64);
    k_attn<<<dim3(BATCH * NTOK / 64), 512, 0, stream>>>(mask64, WhT, s1, s2, out);
}

// Round 7
// 144.873 us; speedup vs baseline: 1.1806x; 1.1806x over previous
//
#include <hip/hip_runtime.h>
#include <hip/hip_fp16.h>

typedef _Float16 f16;
typedef _Float16 half8 __attribute__((ext_vector_type(8)));
typedef float f32x4 __attribute__((ext_vector_type(4)));

#define BATCH 8
#define NTOK 2048
#define FIN 256
#define FOUT 256
#define ALPHA 0.2f
#define WHS 2080   // WhT row stride (pad breaks 4KB power-of-2 stride)

// ---------------- K0: W[k][o] fp32 -> WT[o][k] fp16 ----------------
__global__ void k_wt(const float* __restrict__ W, f16* __restrict__ WT) {
    __shared__ float t[32][33];
    int o0 = blockIdx.x * 32, k0 = blockIdx.y * 32;
    int tx = threadIdx.x, ty = threadIdx.y;
    t[ty][tx] = W[(k0 + ty) * FOUT + o0 + tx];
    __syncthreads();
    WT[(o0 + ty) * FIN + (k0 + tx)] = (f16)t[tx][ty];
}

// ---------------- K1: Wh = x @ W, store WhT[b][o][n] fp16 ----------------
__global__ __launch_bounds__(256) void k_gemm(const float* __restrict__ x,
                                              const f16* __restrict__ WT,
                                              f16* __restrict__ WhT) {
    __shared__ f16 Ah[64][72];
    __shared__ f16 Bt[256][72];
    int m0 = blockIdx.x * 64;
    int t = threadIdx.x;
    int lane = t & 63, w = t >> 6;
    f32x4 acc[4][4] = {};

    for (int k0 = 0; k0 < FIN; k0 += 64) {
        {
            int r = t >> 2, c = (t & 3) * 16;
            const float* src = x + (size_t)(m0 + r) * FIN + k0 + c;
            f16 tmp[16];
#pragma unroll
            for (int q = 0; q < 16; q++) tmp[q] = (f16)src[q];
            *(half8*)&Ah[r][c] = *(half8*)&tmp[0];
            *(half8*)&Ah[r][c + 8] = *(half8*)&tmp[8];
        }
        {
            const f16* src = WT + (size_t)t * FIN + k0;
#pragma unroll
            for (int q = 0; q < 8; q++)
                *(half8*)&Bt[t][q * 8] = *(const half8*)&src[q * 8];
        }
        __syncthreads();
#pragma unroll
        for (int kc = 0; kc < 2; kc++) {
            int krow = kc * 32 + ((lane >> 4) * 8);
            half8 af[4], bf[4];
#pragma unroll
            for (int fi = 0; fi < 4; fi++)
                af[fi] = *(half8*)&Ah[fi * 16 + (lane & 15)][krow];
#pragma unroll
            for (int fo = 0; fo < 4; fo++)
                bf[fo] = *(half8*)&Bt[w * 64 + fo * 16 + (lane & 15)][krow];
#pragma unroll
            for (int fi = 0; fi < 4; fi++)
#pragma unroll
                for (int fo = 0; fo < 4; fo++)
                    acc[fi][fo] = __builtin_amdgcn_mfma_f32_16x16x32_f16(
                        af[fi], bf[fo], acc[fi][fo], 0, 0, 0);
        }
        __syncthreads();
    }
    int b = m0 >> 11;
    int nbase = m0 & (NTOK - 1);
#pragma unroll
    for (int fi = 0; fi < 4; fi++)
#pragma unroll
        for (int fo = 0; fo < 4; fo++) {
            int o = w * 64 + fo * 16 + (lane & 15);
#pragma unroll
            for (int q = 0; q < 4; q++) {
                int n = nbase + fi * 16 + (lane >> 4) * 4 + q;
                WhT[((size_t)b * FOUT + o) * WHS + n] = (f16)acc[fi][fo][q];
            }
        }
}

// ---------------- K2: s1 = Wh@a1, s2 = Wh@a2 ----------------
__global__ __launch_bounds__(256) void k_s12(const f16* __restrict__ WhT,
                                             const float* __restrict__ a,
                                             float* __restrict__ s1,
                                             float* __restrict__ s2) {
    int b = blockIdx.y;
    int n = blockIdx.x * 256 + threadIdx.x;
    const f16* base = WhT + (size_t)b * FOUT * WHS + n;
    float a1 = 0.f, a2 = 0.f;
#pragma unroll 4
    for (int o = 0; o < FOUT; o++) {
        float wh = (float)base[(size_t)o * WHS];
        a1 += wh * a[o];
        a2 += wh * a[FOUT + o];
    }
    s1[b * NTOK + n] = a1;
    s2[b * NTOK + n] = a2;
}

// ---------------- K2b: mrow[b][i] = lrelu(s1[b][i] + max_j s2[b][j]) ----------------
// Upper bound on the row max (lrelu monotone) -> fixed softmax shift, p <= 1.
__global__ __launch_bounds__(256) void k_rowmax(const float* __restrict__ s1,
                                                const float* __restrict__ s2,
                                                float* __restrict__ mrow) {
    __shared__ float red[4];
    int b = blockIdx.x, t = threadIdx.x;
    const float* s2b = s2 + (size_t)b * NTOK;
    float mx = -3.0e38f;
#pragma unroll
    for (int i = 0; i < 8; i++) mx = fmaxf(mx, s2b[t + i * 256]);
#pragma unroll
    for (int d = 1; d < 64; d <<= 1) mx = fmaxf(mx, __shfl_xor(mx, d));
    if ((t & 63) == 0) red[t >> 6] = mx;
    __syncthreads();
    float s2m = fmaxf(fmaxf(red[0], red[1]), fmaxf(red[2], red[3]));
#pragma unroll
    for (int i = 0; i < 8; i++) {
        int n = t + i * 256;
        float s = s1[(size_t)b * NTOK + n] + s2m;
        mrow[(size_t)b * NTOK + n] = fmaxf(s, ALPHA * s);
    }
}

// ---------------- K3: fused adj-read + softmax(fixed shift) + P@Wh + ELU ----------------
// 512 thr = 8 waves, fully independent in the main loop (NO barriers, NO
// cross-lane ops): wave w: jq=w&1 (1024-j half, partials ADD at end),
// oh=w>>1 (64-o quarter). Lane (lr,lg): rows i0+lr / i0+16+lr, k=lg*8+q.
// P built in-register in exact MFMA A-layout. adj streamed raw (no pack
// kernel) with 1-step register prefetch. 128-VGPR cap -> 16 waves/CU.
__global__ __launch_bounds__(512, 4) void k_attn(const int* __restrict__ adj,
                                                 const f16* __restrict__ WhT,
                                                 const float* __restrict__ s1g,
                                                 const float* __restrict__ s2g,
                                                 const float* __restrict__ mg,
                                                 float* __restrict__ out) {
    __shared__ float s2_lds[NTOK];          // 8 KB
    __shared__ float accW[2][32][132];      // 33.8 KB  (2-way-free padded)
    __shared__ float lpart[2][32];

    int b = blockIdx.x & 7;                 // batch -> XCD pinning
    int i0 = (blockIdx.x >> 3) * 32;
    int t = threadIdx.x;
    int lane = t & 63, w = t >> 6;
    int jq = w & 1, oh = w >> 1;
    int lr = lane & 15, lg = lane >> 4;

    ((f32x4*)s2_lds)[t] = ((const f32x4*)(s2g + (size_t)b * NTOK))[t];
    __syncthreads();

    int r0 = i0 + lr, r1 = r0 + 16;
    float s1r0 = s1g[(size_t)b * NTOK + r0];
    float s1r1 = s1g[(size_t)b * NTOK + r1];
    float m0 = mg[(size_t)b * NTOK + r0];
    float m1 = mg[(size_t)b * NTOK + r1];

    const int* ar0 = adj + ((size_t)(b * NTOK + r0)) * NTOK + jq * 1024 + lg * 8;
    const int* ar1 = adj + ((size_t)(b * NTOK + r1)) * NTOK + jq * 1024 + lg * 8;
    const f16* wb = WhT + ((size_t)(b * FOUT + oh * 64 + lr)) * WHS + jq * 1024 + lg * 8;

    f32x4 acc0[4] = {}, acc1[4] = {};
    float l0 = 0.f, l1 = 0.f;

    int4 cA0 = *(const int4*)(ar0), cA1 = *(const int4*)(ar0 + 4);
    int4 cB0 = *(const int4*)(ar1), cB1 = *(const int4*)(ar1 + 4);

    for (int jt = 0; jt < 32; jt++) {
        // B-fragment loads first (independent -> overlap softmax)
        const f16* wj = wb + jt * 32;
        half8 bf0 = *(const half8*)(wj);
        half8 bf1 = *(const half8*)(wj + 16 * WHS);
        half8 bf2 = *(const half8*)(wj + 32 * WHS);
        half8 bf3 = *(const half8*)(wj + 48 * WHS);

        // adj prefetch for next step
        int4 nA0, nA1, nB0, nB1;
        if (jt < 31) {
            nA0 = *(const int4*)(ar0 + (jt + 1) * 32);
            nA1 = *(const int4*)(ar0 + (jt + 1) * 32 + 4);
            nB0 = *(const int4*)(ar1 + (jt + 1) * 32);
            nB1 = *(const int4*)(ar1 + (jt + 1) * 32 + 4);
        } else {
            nA0 = cA0; nA1 = cA1; nB0 = cB0; nB1 = cB1;
        }

        int sb = jq * 1024 + jt * 32 + lg * 8;
        f32x4 sA = *(const f32x4*)&s2_lds[sb];
        f32x4 sB = *(const f32x4*)&s2_lds[sb + 4];
        float sv[8] = {sA[0], sA[1], sA[2], sA[3], sB[0], sB[1], sB[2], sB[3]};

        half8 ph0, ph1;
        {
            int ai[8] = {cA0.x, cA0.y, cA0.z, cA0.w, cA1.x, cA1.y, cA1.z, cA1.w};
#pragma unroll
            for (int q = 0; q < 8; q++) {
                float s = s1r0 + sv[q];
                float ev = fmaxf(s, ALPHA * s);
                float p = (ai[q] > 0) ? __expf(ev - m0) : 0.f;
                l0 += p;
                ph0[q] = (f16)p;
            }
        }
        {
            int ai[8] = {cB0.x, cB0.y, cB0.z, cB0.w, cB1.x, cB1.y, cB1.z, cB1.w};
#pragma unroll
            for (int q = 0; q < 8; q++) {
                float s = s1r1 + sv[q];
                float ev = fmaxf(s, ALPHA * s);
                float p = (ai[q] > 0) ? __expf(ev - m1) : 0.f;
                l1 += p;
                ph1[q] = (f16)p;
            }
        }

        acc0[0] = __builtin_amdgcn_mfma_f32_16x16x32_f16(ph0, bf0, acc0[0], 0, 0, 0);
        acc1[0] = __builtin_amdgcn_mfma_f32_16x16x32_f16(ph1, bf0, acc1[0], 0, 0, 0);
        acc0[1] = __builtin_amdgcn_mfma_f32_16x16x32_f16(ph0, bf1, acc0[1], 0, 0, 0);
        acc1[1] = __builtin_amdgcn_mfma_f32_16x16x32_f16(ph1, bf1, acc1[1], 0, 0, 0);
        acc0[2] = __builtin_amdgcn_mfma_f32_16x16x32_f16(ph0, bf2, acc0[2], 0, 0, 0);
        acc1[2] = __builtin_amdgcn_mfma_f32_16x16x32_f16(ph1, bf2, acc1[2], 0, 0, 0);
        acc0[3] = __builtin_amdgcn_mfma_f32_16x16x32_f16(ph0, bf3, acc0[3], 0, 0, 0);
        acc1[3] = __builtin_amdgcn_mfma_f32_16x16x32_f16(ph1, bf3, acc1[3], 0, 0, 0);

        cA0 = nA0; cA1 = nA1; cB0 = nB0; cB1 = nB1;
    }

    // row-sum reduce over the 4 k-lane-groups (once, outside the loop)
    l0 += __shfl_xor(l0, 16); l0 += __shfl_xor(l0, 32);
    l1 += __shfl_xor(l1, 16); l1 += __shfl_xor(l1, 32);
    if (oh == 0 && lane < 16) { lpart[jq][lr] = l0; lpart[jq][16 + lr] = l1; }
    __syncthreads();

    // combine jq partials (plain ADD — fixed shift) + divide + ELU + store
#pragma unroll
    for (int h = 0; h < 2; h++) {
        if ((oh >> 1) == h) {
            int cb = (oh & 1) * 64;
#pragma unroll
            for (int k = 0; k < 4; k++)
#pragma unroll
                for (int q = 0; q < 4; q++) {
                    accW[jq][lg * 4 + q][cb + k * 16 + lr] = acc0[k][q];
                    accW[jq][16 + lg * 4 + q][cb + k * 16 + lr] = acc1[k][q];
                }
        }
        __syncthreads();
        {
            int row = w * 4 + lg;
            int c = lr * 8;
            f32x4 va = *(const f32x4*)&accW[0][row][c] + *(const f32x4*)&accW[1][row][c];
            f32x4 vb = *(const f32x4*)&accW[0][row][c + 4] + *(const f32x4*)&accW[1][row][c + 4];
            float rl = 1.f / (lpart[0][row] + lpart[1][row]);
            f32x4 oa, ob;
#pragma unroll
            for (int q = 0; q < 4; q++) {
                float u = va[q] * rl;
                oa[q] = u > 0.f ? u : __expf(u) - 1.f;
                float v = vb[q] * rl;
                ob[q] = v > 0.f ? v : __expf(v) - 1.f;
            }
            float* op = out + ((size_t)(b * NTOK + i0 + row)) * FOUT + h * 128 + c;
            __builtin_nontemporal_store(oa, (f32x4*)op);
            __builtin_nontemporal_store(ob, (f32x4*)(op + 4));
        }
        __syncthreads();
    }
}

extern "C" void kernel_launch(void* const* d_in, const int* in_sizes, int n_in,
                              void* d_out, int out_size, void* d_ws, size_t ws_size,
                              hipStream_t stream) {
    const float* x = (const float*)d_in[0];
    const int* adj = (const int*)d_in[1];
    const float* W = (const float*)d_in[2];
    const float* a = (const float*)d_in[3];
    float* out = (float*)d_out;

    char* ws = (char*)d_ws;
    f16* WT = (f16*)ws;                                     // 128 KB
    f16* WhT = (f16*)(ws + 131072);                         // 8.13 MB
    float* s1 = (float*)(ws + 131072 + 8519680);            // 64 KB
    float* s2 = s1 + BATCH * NTOK;                          // 64 KB
    float* mrow = s2 + BATCH * NTOK;                        // 64 KB

    k_wt<<<dim3(FOUT / 32, FIN / 32), dim3(32, 32), 0, stream>>>(W, WT);
    k_gemm<<<dim3(BATCH * NTOK / 64), 256, 0, stream>>>(x, WT, WhT);
    k_s12<<<dim3(NTOK / 256, BATCH), 256, 0, stream>>>(WhT, a, s1, s2);
    k_rowmax<<<dim3(BATCH), 256, 0, stream>>>(s1, s2, mrow);
    k_attn<<<dim3(BATCH * NTOK / 32), 512, 0, stream>>>(adj, WhT, s1, s2, mrow, out);
}

// Round 8
// 125.659 us; speedup vs baseline: 1.3611x; 1.1529x over previous
//
#include <hip/hip_runtime.h>
#include <hip/hip_fp16.h>

typedef _Float16 f16;
typedef _Float16 half8 __attribute__((ext_vector_type(8)));
typedef float f32x4 __attribute__((ext_vector_type(4)));

#define BATCH 8
#define NTOK 2048
#define FIN 256
#define FOUT 256
#define ALPHA 0.2f
#define WHS 2080   // WhT row stride (pad breaks 4KB power-of-2 stride)

// ---------------- K0: W[k][o] fp32 -> WT[o][k] fp16 ----------------
__global__ void k_wt(const float* __restrict__ W, f16* __restrict__ WT) {
    __shared__ float t[32][33];
    int o0 = blockIdx.x * 32, k0 = blockIdx.y * 32;
    int tx = threadIdx.x, ty = threadIdx.y;
    t[ty][tx] = W[(k0 + ty) * FOUT + o0 + tx];
    __syncthreads();
    WT[(o0 + ty) * FIN + (k0 + tx)] = (f16)t[tx][ty];
}

// ---------------- K pack: adj int32 -> bitmask (dedicated streamer) ----------------
__global__ __launch_bounds__(256) void k_pack(const int* __restrict__ adj,
                                              unsigned long long* __restrict__ mask) {
    int lane = threadIdx.x & 63;
    size_t wv = (((size_t)blockIdx.x * 256 + threadIdx.x) >> 6);
    for (int it = 0; it < 8; it++) {
        size_t wave = wv + (size_t)it * 16384;
        const int* base = adj + wave * 256;
        unsigned long long m0 = __ballot(base[lane] > 0);
        unsigned long long m1 = __ballot(base[64 + lane] > 0);
        unsigned long long m2 = __ballot(base[128 + lane] > 0);
        unsigned long long m3 = __ballot(base[192 + lane] > 0);
        if (lane < 4) {
            unsigned long long v = lane == 0 ? m0 : lane == 1 ? m1 : lane == 2 ? m2 : m3;
            mask[wave * 4 + lane] = v;
        }
    }
}

// ---------------- K1: Wh = x @ W, store WhT[b][o][n] fp16 ----------------
__global__ __launch_bounds__(256) void k_gemm(const float* __restrict__ x,
                                              const f16* __restrict__ WT,
                                              f16* __restrict__ WhT) {
    __shared__ f16 Ah[64][72];
    __shared__ f16 Bt[256][72];
    int m0 = blockIdx.x * 64;
    int t = threadIdx.x;
    int lane = t & 63, w = t >> 6;
    f32x4 acc[4][4] = {};

    for (int k0 = 0; k0 < FIN; k0 += 64) {
        {
            int r = t >> 2, c = (t & 3) * 16;
            const float* src = x + (size_t)(m0 + r) * FIN + k0 + c;
            f16 tmp[16];
#pragma unroll
            for (int q = 0; q < 16; q++) tmp[q] = (f16)src[q];
            *(half8*)&Ah[r][c] = *(half8*)&tmp[0];
            *(half8*)&Ah[r][c + 8] = *(half8*)&tmp[8];
        }
        {
            const f16* src = WT + (size_t)t * FIN + k0;
#pragma unroll
            for (int q = 0; q < 8; q++)
                *(half8*)&Bt[t][q * 8] = *(const half8*)&src[q * 8];
        }
        __syncthreads();
#pragma unroll
        for (int kc = 0; kc < 2; kc++) {
            int krow = kc * 32 + ((lane >> 4) * 8);
            half8 af[4], bf[4];
#pragma unroll
            for (int fi = 0; fi < 4; fi++)
                af[fi] = *(half8*)&Ah[fi * 16 + (lane & 15)][krow];
#pragma unroll
            for (int fo = 0; fo < 4; fo++)
                bf[fo] = *(half8*)&Bt[w * 64 + fo * 16 + (lane & 15)][krow];
#pragma unroll
            for (int fi = 0; fi < 4; fi++)
#pragma unroll
                for (int fo = 0; fo < 4; fo++)
                    acc[fi][fo] = __builtin_amdgcn_mfma_f32_16x16x32_f16(
                        af[fi], bf[fo], acc[fi][fo], 0, 0, 0);
        }
        __syncthreads();
    }
    int b = m0 >> 11;
    int nbase = m0 & (NTOK - 1);
#pragma unroll
    for (int fi = 0; fi < 4; fi++)
#pragma unroll
        for (int fo = 0; fo < 4; fo++) {
            int o = w * 64 + fo * 16 + (lane & 15);
#pragma unroll
            for (int q = 0; q < 4; q++) {
                int n = nbase + fi * 16 + (lane >> 4) * 4 + q;
                WhT[((size_t)b * FOUT + o) * WHS + n] = (f16)acc[fi][fo][q];
            }
        }
}

// ---------------- K2: s1 = Wh@a1, s2 = Wh@a2 ----------------
__global__ __launch_bounds__(256) void k_s12(const f16* __restrict__ WhT,
                                             const float* __restrict__ a,
                                             float* __restrict__ s1,
                                             float* __restrict__ s2) {
    int b = blockIdx.y;
    int n = blockIdx.x * 256 + threadIdx.x;
    const f16* base = WhT + (size_t)b * FOUT * WHS + n;
    float a1 = 0.f, a2 = 0.f;
#pragma unroll 4
    for (int o = 0; o < FOUT; o++) {
        float wh = (float)base[(size_t)o * WHS];
        a1 += wh * a[o];
        a2 += wh * a[FOUT + o];
    }
    s1[b * NTOK + n] = a1;
    s2[b * NTOK + n] = a2;
}

// ---------------- K2b: mrow[b][i] = lrelu(s1[b][i] + max_j s2[b][j]) ----------------
// Upper bound on the row max (lrelu monotone) -> fixed softmax shift, p <= 1.
__global__ __launch_bounds__(256) void k_rowmax(const float* __restrict__ s1,
                                                const float* __restrict__ s2,
                                                float* __restrict__ mrow) {
    __shared__ float red[4];
    int b = blockIdx.x, t = threadIdx.x;
    const float* s2b = s2 + (size_t)b * NTOK;
    float mx = -3.0e38f;
#pragma unroll
    for (int i = 0; i < 8; i++) mx = fmaxf(mx, s2b[t + i * 256]);
#pragma unroll
    for (int d = 1; d < 64; d <<= 1) mx = fmaxf(mx, __shfl_xor(mx, d));
    if ((t & 63) == 0) red[t >> 6] = mx;
    __syncthreads();
    float s2m = fmaxf(fmaxf(red[0], red[1]), fmaxf(red[2], red[3]));
#pragma unroll
    for (int i = 0; i < 8; i++) {
        int n = t + i * 256;
        float s = s1[(size_t)b * NTOK + n] + s2m;
        mrow[(size_t)b * NTOK + n] = fmaxf(s, ALPHA * s);
    }
}

// ---------------- K3: fused softmax(fixed shift) + P@Wh + ELU ----------------
// 512 thr = 8 waves, fully independent in the main loop (NO barriers, NO
// cross-lane ops): wave w: jq=w&1 (1024-j half, partials ADD at end),
// oh=w>>1 (64-o quarter). Lane (lr,lg): rows i0+lr / i0+16+lr, k=lg*8+q.
// P built in-register in exact MFMA A-layout; adjacency from packed bitmask
// (one u64 per row per 2 iters, L1-broadcast). 128-VGPR cap -> 16 waves/CU.
__global__ __launch_bounds__(512, 4) void k_attn(const unsigned long long* __restrict__ mask,
                                                 const f16* __restrict__ WhT,
                                                 const float* __restrict__ s1g,
                                                 const float* __restrict__ s2g,
                                                 const float* __restrict__ mg,
                                                 float* __restrict__ out) {
    __shared__ float s2_lds[NTOK];          // 8 KB
    __shared__ float accW[2][32][132];      // 33.8 KB
    __shared__ float lpart[2][32];

    int b = blockIdx.x & 7;                 // batch -> XCD pinning
    int i0 = (blockIdx.x >> 3) * 32;
    int t = threadIdx.x;
    int lane = t & 63, w = t >> 6;
    int jq = w & 1, oh = w >> 1;
    int lr = lane & 15, lg = lane >> 4;

    ((f32x4*)s2_lds)[t] = ((const f32x4*)(s2g + (size_t)b * NTOK))[t];
    __syncthreads();

    int r0 = i0 + lr, r1 = r0 + 16;
    float s1r0 = s1g[(size_t)b * NTOK + r0];
    float s1r1 = s1g[(size_t)b * NTOK + r1];
    float m0 = mg[(size_t)b * NTOK + r0];
    float m1 = mg[(size_t)b * NTOK + r1];

    const unsigned long long* mr0 = mask + ((size_t)(b * NTOK + r0)) * 32 + jq * 16;
    const unsigned long long* mr1 = mask + ((size_t)(b * NTOK + r1)) * 32 + jq * 16;
    const f16* wb = WhT + ((size_t)(b * FOUT + oh * 64 + lr)) * WHS + jq * 1024 + lg * 8;

    f32x4 acc0[4] = {}, acc1[4] = {};
    float l0 = 0.f, l1 = 0.f;

    unsigned long long mw0 = mr0[0], mw1 = mr1[0];
    unsigned long long nx0 = 0, nx1 = 0;

    for (int jt = 0; jt < 32; jt++) {
        // B-fragment loads first (independent -> latency hides under softmax)
        const f16* wj = wb + jt * 32;
        half8 bf0 = *(const half8*)(wj);
        half8 bf1 = *(const half8*)(wj + 16 * WHS);
        half8 bf2 = *(const half8*)(wj + 32 * WHS);
        half8 bf3 = *(const half8*)(wj + 48 * WHS);

        if ((jt & 1) == 0 && jt < 30) {     // prefetch next u64 pair
            nx0 = mr0[(jt >> 1) + 1];
            nx1 = mr1[(jt >> 1) + 1];
        }
        int sh2 = ((jt & 1) << 5) + (lg << 3);
        unsigned bits0 = (unsigned)(mw0 >> sh2) & 0xffu;
        unsigned bits1 = (unsigned)(mw1 >> sh2) & 0xffu;

        int sb = jq * 1024 + jt * 32 + lg * 8;
        f32x4 sA = *(const f32x4*)&s2_lds[sb];
        f32x4 sB = *(const f32x4*)&s2_lds[sb + 4];
        float sv[8] = {sA[0], sA[1], sA[2], sA[3], sB[0], sB[1], sB[2], sB[3]};

        half8 ph0, ph1;
#pragma unroll
        for (int q = 0; q < 8; q++) {
            float s = s1r0 + sv[q];
            float ev = fmaxf(s, ALPHA * s);
            float p = ((bits0 >> q) & 1) ? __expf(ev - m0) : 0.f;
            l0 += p;
            ph0[q] = (f16)p;
        }
#pragma unroll
        for (int q = 0; q < 8; q++) {
            float s = s1r1 + sv[q];
            float ev = fmaxf(s, ALPHA * s);
            float p = ((bits1 >> q) & 1) ? __expf(ev - m1) : 0.f;
            l1 += p;
            ph1[q] = (f16)p;
        }

        acc0[0] = __builtin_amdgcn_mfma_f32_16x16x32_f16(ph0, bf0, acc0[0], 0, 0, 0);
        acc1[0] = __builtin_amdgcn_mfma_f32_16x16x32_f16(ph1, bf0, acc1[0], 0, 0, 0);
        acc0[1] = __builtin_amdgcn_mfma_f32_16x16x32_f16(ph0, bf1, acc0[1], 0, 0, 0);
        acc1[1] = __builtin_amdgcn_mfma_f32_16x16x32_f16(ph1, bf1, acc1[1], 0, 0, 0);
        acc0[2] = __builtin_amdgcn_mfma_f32_16x16x32_f16(ph0, bf2, acc0[2], 0, 0, 0);
        acc1[2] = __builtin_amdgcn_mfma_f32_16x16x32_f16(ph1, bf2, acc1[2], 0, 0, 0);
        acc0[3] = __builtin_amdgcn_mfma_f32_16x16x32_f16(ph0, bf3, acc0[3], 0, 0, 0);
        acc1[3] = __builtin_amdgcn_mfma_f32_16x16x32_f16(ph1, bf3, acc1[3], 0, 0, 0);

        if (jt & 1) { mw0 = nx0; mw1 = nx1; }
    }

    // row-sum reduce over the 4 k-lane-groups (once, outside the loop)
    l0 += __shfl_xor(l0, 16); l0 += __shfl_xor(l0, 32);
    l1 += __shfl_xor(l1, 16); l1 += __shfl_xor(l1, 32);
    if (oh == 0 && lane < 16) { lpart[jq][lr] = l0; lpart[jq][16 + lr] = l1; }
    __syncthreads();

    // combine jq partials (plain ADD — fixed shift) + divide + ELU + store
#pragma unroll
    for (int h = 0; h < 2; h++) {
        if ((oh >> 1) == h) {
            int cb = (oh & 1) * 64;
#pragma unroll
            for (int k = 0; k < 4; k++)
#pragma unroll
                for (int q = 0; q < 4; q++) {
                    accW[jq][lg * 4 + q][cb + k * 16 + lr] = acc0[k][q];
                    accW[jq][16 + lg * 4 + q][cb + k * 16 + lr] = acc1[k][q];
                }
        }
        __syncthreads();
        {
            int row = w * 4 + lg;
            int c = lr * 8;
            f32x4 va = *(const f32x4*)&accW[0][row][c] + *(const f32x4*)&accW[1][row][c];
            f32x4 vb = *(const f32x4*)&accW[0][row][c + 4] + *(const f32x4*)&accW[1][row][c + 4];
            float rl = 1.f / (lpart[0][row] + lpart[1][row]);
            f32x4 oa, ob;
#pragma unroll
            for (int q = 0; q < 4; q++) {
                float u = va[q] * rl;
                oa[q] = u > 0.f ? u : __expf(u) - 1.f;
                float v = vb[q] * rl;
                ob[q] = v > 0.f ? v : __expf(v) - 1.f;
            }
            float* op = out + ((size_t)(b * NTOK + i0 + row)) * FOUT + h * 128 + c;
            __builtin_nontemporal_store(oa, (f32x4*)op);
            __builtin_nontemporal_store(ob, (f32x4*)(op + 4));
        }
        __syncthreads();
    }
}

extern "C" void kernel_launch(void* const* d_in, const int* in_sizes, int n_in,
                              void* d_out, int out_size, void* d_ws, size_t ws_size,
                              hipStream_t stream) {
    const float* x = (const float*)d_in[0];
    const int* adj = (const int*)d_in[1];
    const float* W = (const float*)d_in[2];
    const float* a = (const float*)d_in[3];
    float* out = (float*)d_out;

    char* ws = (char*)d_ws;
    f16* WT = (f16*)ws;                                     // 128 KB
    f16* WhT = (f16*)(ws + 131072);                         // 8.13 MB
    float* s1 = (float*)(ws + 131072 + 8519680);            // 64 KB
    float* s2 = s1 + BATCH * NTOK;                          // 64 KB
    float* mrow = s2 + BATCH * NTOK;                        // 64 KB
    unsigned long long* mask64 =
        (unsigned long long*)(ws + 131072 + 8519680 + 196608);  // 4 MB

    k_wt<<<dim3(FOUT / 32, FIN / 32), dim3(32, 32), 0, stream>>>(W, WT);
    k_gemm<<<dim3(BATCH * NTOK / 64), 256, 0, stream>>>(x, WT, WhT);
    k_s12<<<dim3(NTOK / 256, BATCH), 256, 0, stream>>>(WhT, a, s1, s2);
    k_rowmax<<<dim3(BATCH), 256, 0, stream>>>(s1, s2, mrow);
    k_pack<<<dim3(4096), 256, 0, stream>>>(adj, mask64);
    k_attn<<<dim3(BATCH * NTOK / 32), 512, 0, stream>>>(mask64, WhT, s1, s2, mrow, out);
}